// Round 11
// baseline (32.163 us; speedup 1.0000x reference)
//
#include <hip/hip_runtime.h>

#define HW (128*128)
#define CHW (64*HW)

typedef _Float16 h2 __attribute__((ext_vector_type(2)));
typedef _Float16 h4 __attribute__((ext_vector_type(4)));
typedef _Float16 h8 __attribute__((ext_vector_type(8)));
typedef float f32x4 __attribute__((ext_vector_type(4)));

union H8P { h8 v; h2 p[4]; };
union H4P { h4 v; h2 p[2]; int2 i; };

#if !__has_builtin(__builtin_amdgcn_fdot2)
__device__ __forceinline__ float __builtin_amdgcn_fdot2(h2 a, h2 b, float c, bool) {
  return c + (float)a[0]*(float)b[0] + (float)a[1]*(float)b[1];
}
#endif

// ---------------- transpose + setup fused (R10-proven) ----------------
__global__ __launch_bounds__(256) void prep_kernel(
    const float* __restrict__ x, _Float16* __restrict__ xt,
    const float* __restrict__ alpha,
    const float* __restrict__ q_dw, const float* __restrict__ q_pw, const float* __restrict__ q_pb,
    const float* __restrict__ k_dw, const float* __restrict__ k_pw,
    const float* __restrict__ offw, const float* __restrict__ offb,
    const float* __restrict__ v_dw, const float* __restrict__ v_pw, const float* __restrict__ v_pb,
    const float* __restrict__ o_dw, const float* __restrict__ o_pw, const float* __restrict__ o_pb,
    _Float16* __restrict__ Apack2, _Float16* __restrict__ Apack6,
    float* __restrict__ bias96, float* __restrict__ boutd)
{
  int tid = threadIdx.x;
  if (blockIdx.x < 1024) {
    __shared__ __align__(16) float t[64][68];
    int i0 = blockIdx.x;
    int blk = (i0 & 7)*128 + (i0 >> 3);
    int b = blk >> 8; int y = (blk >> 1) & 127; int x0 = (blk & 1) << 6;
    const float* xb = x + b*CHW + y*128 + x0;
    {
      int c = tid >> 2, q = tid & 3;
      const float4* srcv = (const float4*)(xb + c*HW + q*16);
      float4* dst = (float4*)&t[c][q*16];
      #pragma unroll
      for (int i = 0; i < 4; ++i) dst[i] = srcv[i];
    }
    __syncthreads();
    {
      int p = tid >> 2, hc = tid & 3;
      h8 o0, o1;
      #pragma unroll
      for (int j = 0; j < 8; ++j) o0[j] = (_Float16)t[hc*16 + j][p];
      #pragma unroll
      for (int j = 0; j < 8; ++j) o1[j] = (_Float16)t[hc*16 + 8 + j][p];
      h8* dstg = (h8*)(xt + (size_t)(b*HW + y*128 + x0 + p)*64 + hc*16);
      dstg[0] = o0; dstg[1] = o1;
    }
    return;
  }
  int bb = blockIdx.x - 1024;
  float a = alpha[0];
  if (bb < 24) {                       // Apack2: [6 mt][2 kt][64 lane][8]
    int e = bb*256 + tid;
    int j = e & 7, l = (e >> 3) & 63, kt = (e >> 9) & 1, mt = e >> 10;
    int row = mt*16 + (l & 15);
    int c   = kt*32 + (l >> 4)*8 + j;
    float v = 0.f;
    if (row < 64) {
      float s = 0.f;
      for (int o = 0; o < 64; ++o) s += k_pw[o*64+row]*q_pw[o*64+c];
      v = k_dw[row]*q_dw[c]*s;
    } else if (row < 82) {
      v = offw[(row-64)*64 + c];
    }
    Apack2[e] = (_Float16)v;
  } else if (bb < 56) {                // Apack6: [4 mt][4 kt][64 lane][8]
    int e = (bb-24)*256 + tid;
    int j = e & 7, l = (e >> 3) & 63, kt = (e >> 9) & 3, mt = e >> 11;
    int o  = mt*16 + (l & 15);
    int cc = kt*32 + (l >> 4)*8 + j;
    float v;
    if (cc < 64) {
      float s = 0.f;
      for (int h = 0; h < 64; ++h) s += o_pw[o*64+h]*o_dw[h]*v_pw[h*64+cc];
      v = a*v_dw[cc]*s;
    } else {
      int c2 = cc - 64;
      float s = 0.f;
      for (int h = 0; h < 64; ++h) s += o_pw[o*64+h]*o_dw[h]*q_pw[h*64+c2];
      v = q_dw[c2]*s;
    }
    Apack6[e] = (_Float16)v;
  } else {
    if (tid < 96) {
      float v = 0.f;
      if (tid < 64) {
        float s = 0.f;
        for (int o = 0; o < 64; ++o) s += k_pw[o*64+tid]*q_pb[o];
        v = k_dw[tid]*s;
      } else if (tid < 82) {
        v = offb[tid-64];
      }
      bias96[tid] = v;
    } else if (tid >= 128 && tid < 192) {
      int o = tid - 128;
      float s2 = 0.f;
      for (int h = 0; h < 64; ++h) s2 += o_pw[o*64+h]*o_dw[h]*(a*v_pb[h]+q_pb[h]);
      boutd[o] = o_pb[o] + s2;
    }
  }
}

// ---------------- fused main kernel: 64 px/block, 512 threads ------------------
// LDS (78336 B):
//  win  [0,55296):      6x72 px window, 64ch f16, 16B-granule XOR-swizzled by (pix&7)
//  qkL  [55296,64512):  f16 [64][72] (P2..hoist) | qs (P5..P6)
//  offsF[64512,69120):  f32 [18][64]  (P2..P2.5)
//  prm  [69120,78336):  int4[576]     (P2.5..P3)
// Gathers hit the LDS window when contained (typical); global-xt fallback otherwise.
__global__ __launch_bounds__(512, 4) void dam_kernel(
  const _Float16* __restrict__ xt,
  const _Float16* __restrict__ Apack2, const _Float16* __restrict__ Apack6,
  const float* __restrict__ bias96, const float* __restrict__ boutd,
  float* __restrict__ out)
{
  __shared__ __align__(16) char lds[78336];
  _Float16* win       = (_Float16*)lds;
  _Float16 (*qkL)[72] = (_Float16 (*)[72])(lds + 55296);
  _Float16 (*qs)[72]  = (_Float16 (*)[72])(lds + 55296);
  float (*offsF)[64]  = (float (*)[64])(lds + 64512);
  int4* prm           = (int4*)(lds + 69120);          // [576]

  int i0 = blockIdx.x;
  int blk = (i0 & 7)*128 + (i0 >> 3);      // XCD swizzle (matches prep)
  int b = blk >> 8; int y = (blk >> 1) & 127; int x0 = (blk & 1) << 6;
  int tid = threadIdx.x;
  int g = tid >> 6;
  int wg = __builtin_amdgcn_readfirstlane(g);
  int lane = tid & 63;

  // window base (speculative; containment checked exactly in P2.5)
  int bx = (int)floorf((float)x0 * (128.0f/127.0f) - 0.5f) - 2;
  bx = min(max(bx, 0), 128 - 72);
  int by = (int)floorf((float)y * (128.0f/127.0f) - 0.5f) - 2;
  by = min(max(by, 0), 128 - 6);

  // ---- P1: stage 6x72 window from xt, XOR-swizzled granules ----
  {
    const _Float16* srcbase = xt + (size_t)b*HW*64;
    #pragma unroll
    for (int u7 = 0; u7 < 7; ++u7) {
      int u = tid + u7*512;
      if (u < 3456) {                      // 16B units: 6 rows * 72 px * 8 granules
        int pix = u >> 3;                  // window pixel 0..431
        int gph = u & 7;                   // channel granule
        int wr = pix / 72;
        int wc = pix - wr*72;
        h8 v = *(const h8*)(srcbase + ((by + wr)*128 + bx + wc)*64 + gph*8);
        *(h8*)&win[(pix << 6) + ((gph ^ (pix & 7)) << 3)] = v;
      }
    }
  }
  __syncthreads();

  int wyp = y - by;          // tile row in window
  int wxb = x0 - bx;         // tile col0 in window

  // ---- P2: [qk | offsets] = A2 @ x_tile via MFMA (B-frags from win). M=96,K=64,N=64 ----
  {
    const h8* A2 = (const h8*)Apack2;
    #pragma unroll
    for (int i = 0; i < 3; ++i) {
      int t = wg*3 + i; int m = t >> 2, n = t & 3;
      int row0 = m*16 + (lane >> 4)*4;
      int pcol = n*16 + (lane & 15);
      int wpix = wyp*72 + wxb + pcol;
      int sz = wpix & 7;
      f32x4 acc;
      #pragma unroll
      for (int r = 0; r < 4; ++r) acc[r] = bias96[row0 + r];
      h8 b0 = *(const h8*)&win[(wpix << 6) + ((((lane >> 4)    ) ^ sz) << 3)];
      h8 b1 = *(const h8*)&win[(wpix << 6) + ((((lane >> 4) + 4) ^ sz) << 3)];
      acc = __builtin_amdgcn_mfma_f32_16x16x32_f16(A2[(m*2+0)*64 + lane], b0, acc, 0, 0, 0);
      acc = __builtin_amdgcn_mfma_f32_16x16x32_f16(A2[(m*2+1)*64 + lane], b1, acc, 0, 0, 0);
      if (m < 4) {
        h4 v;
        #pragma unroll
        for (int r = 0; r < 4; ++r) v[r] = (_Float16)acc[r];
        *(h4*)&qkL[pcol][m*16 + (lane >> 4)*4] = v;
      } else {
        #pragma unroll
        for (int r = 0; r < 4; ++r) {
          int row = row0 + r;
          if (row < 82) offsF[row - 64][pcol] = acc[r];
        }
      }
    }
  }
  __syncthreads();

  // ---- P2.5: per-(k,p) sampling params computed ONCE -> prm[576] ----
  #pragma unroll
  for (int pass = 0; pass < 2; ++pass) {
    int e = tid + pass*512;
    if (e < 576) {
      int k = e >> 6, pp = e & 63;
      float dx = offsF[k][pp];
      float dy = offsF[9+k][pp];
      float fx = (float)(x0 + pp);
      float fy = (float)y;
      float gx = 2.0f*(fx + dx)/127.0f - 1.0f;
      float gy = 2.0f*(fy + dy)/127.0f - 1.0f;
      float ix = ((gx + 1.0f)*128.0f - 1.0f)*0.5f;
      float iy = ((gy + 1.0f)*128.0f - 1.0f)*0.5f;
      float x0f = floorf(ix), y0f = floorf(iy);
      float wx = ix - x0f, wy = iy - y0f;
      int xi = (int)x0f, yi = (int)y0f;
      bool vx0 = (xi >= 0) && (xi < 128);
      bool vx1 = (xi >= -1) && (xi < 127);
      bool vy0 = (yi >= 0) && (yi < 128);
      bool vy1 = (yi >= -1) && (yi < 127);
      H4P w;
      w.v[0] = (_Float16)((1.f-wy)*(1.f-wx)*((vy0&&vx0)?1.f:0.f));
      w.v[1] = (_Float16)((1.f-wy)*wx      *((vy0&&vx1)?1.f:0.f));
      w.v[2] = (_Float16)(wy*(1.f-wx)      *((vy1&&vx0)?1.f:0.f));
      w.v[3] = (_Float16)(wy*wx            *((vy1&&vx1)?1.f:0.f));
      int xc0 = min(max(xi,0),127), xc1 = min(max(xi+1,0),127);
      int yc0 = min(max(yi,0),127), yc1 = min(max(yi+1,0),127);
      int wx0 = xc0 - bx, wx1 = xc1 - bx;
      int wy0 = yc0 - by, wy1 = yc1 - by;
      bool inside = (wx0 >= 0) && (wx1 <= 71) && (wy0 >= 0) && (wy1 <= 5);
      int4 pr;
      if (inside) {
        pr.x = (int)(0x80000000u | (unsigned)((wy0*72 + wx0)*64));
        pr.y = (wx1 - wx0)*64 | (((wy1 - wy0)*72*64) << 16);
      } else {
        pr.x = (yc0*128 + xc0)*64;
        pr.y = (xc1 - xc0)*64 | (((yc1 - yc0)*8192) << 16);
      }
      pr.z = w.i.x;
      pr.w = w.i.y;
      prm[e] = pr;
    }
  }
  // lane mapping for P3: pixel pxl, channel chunk ch8
  int pxl = wg*8 + (lane >> 3);
  int ch8 = (lane & 7)*8;
  H8P qkh; qkh.v = *(const h8*)&qkL[pxl][ch8];
  __syncthreads();      // prm ready; qkL reads done

  const _Float16* xtb = xt + (size_t)b*HW*64 + ch8;
  int gch = lane & 7;

  // ---- P3: sampling from LDS window (global fallback for escapes) ----
  h2 smp[9][4];
  float sarr[9];
  #pragma unroll
  for (int k = 0; k < 9; ++k) {
    int4 pr = prm[k*64 + pxl];
    H4P w; w.i.x = pr.z; w.i.y = pr.w;
    int dxs = pr.y & 0xFFFF;
    int dys = pr.y >> 16;
    H8P A, Bc, Cc, D;
    if (pr.x < 0) {
      int base = pr.x & 0x7FFFFFFF;
      int pixA = base >> 6;
      int dpx = dxs >> 6;
      int pixB = pixA + dpx;
      int pixC = pixA + (dys >> 6);
      int pixD = pixC + dpx;
      A.v  = *(const h8*)&win[(pixA << 6) + ((gch ^ (pixA & 7)) << 3)];
      Bc.v = *(const h8*)&win[(pixB << 6) + ((gch ^ (pixB & 7)) << 3)];
      Cc.v = *(const h8*)&win[(pixC << 6) + ((gch ^ (pixC & 7)) << 3)];
      D.v  = *(const h8*)&win[(pixD << 6) + ((gch ^ (pixD & 7)) << 3)];
    } else {
      const _Float16* basep = xtb + pr.x;
      A.v  = *(const h8*)(basep);
      Bc.v = *(const h8*)(basep + dxs);
      Cc.v = *(const h8*)(basep + dys);
      D.v  = *(const h8*)(basep + dys + dxs);
    }
    h2 w0h; w0h[0] = w.v[0]; w0h[1] = w.v[0];
    h2 w1h; w1h[0] = w.v[1]; w1h[1] = w.v[1];
    h2 w2h; w2h[0] = w.v[2]; w2h[1] = w.v[2];
    h2 w3h; w3h[0] = w.v[3]; w3h[1] = w.v[3];
    float s = 0.f;
    #pragma unroll
    for (int j = 0; j < 4; ++j) {
      h2 v = A.p[j]*w0h + Bc.p[j]*w1h + Cc.p[j]*w2h + D.p[j]*w3h;
      smp[k][j] = v;
      s = __builtin_amdgcn_fdot2(v, qkh.p[j], s, false);
    }
    s += __shfl_xor(s, 1, 64);
    s += __shfl_xor(s, 2, 64);
    s += __shfl_xor(s, 4, 64);
    sarr[k] = s;
  }

  // ---- P4: softmax over k, fully register-local ----
  float m = sarr[0];
  #pragma unroll
  for (int k = 1; k < 9; ++k) m = fmaxf(m, sarr[k]);
  float ssum = 0.f;
  #pragma unroll
  for (int k = 0; k < 9; ++k) { float e2 = __expf(sarr[k]-m); ssum += e2; sarr[k] = e2; }
  float inv = 1.f/ssum;

  // ---- P5: S = sum_k attn_k * smp_k (registers); write S tile (aliases qkL) ----
  h2 S2[4];
  #pragma unroll
  for (int j = 0; j < 4; ++j) { S2[j][0] = (_Float16)0.f; S2[j][1] = (_Float16)0.f; }
  #pragma unroll
  for (int k = 0; k < 9; ++k) {
    _Float16 akh = (_Float16)(sarr[k]*inv);
    h2 ak; ak[0] = akh; ak[1] = akh;
    #pragma unroll
    for (int j = 0; j < 4; ++j) S2[j] = S2[j] + ak*smp[k][j];
  }
  // qkL has no readers after the P2.5 barrier -> safe to write qs without a pre-barrier
  {
    H8P sv;
    sv.p[0] = S2[0]; sv.p[1] = S2[1]; sv.p[2] = S2[2]; sv.p[3] = S2[3];
    *(h8*)&qs[pxl][ch8] = sv.v;
  }
  __syncthreads();

  // ---- P6: out = A6 @ [S; x] + bout via MFMA (x-frags from win). M=64,K=128,N=64 ----
  {
    const h8* A6 = (const h8*)Apack6;
    float* ob = out + b*CHW + y*128 + x0;
    #pragma unroll
    for (int i = 0; i < 2; ++i) {
      int t = wg*2 + i; int m2 = t >> 2, n = t & 3;
      int row0 = m2*16 + (lane >> 4)*4;
      int pcol = n*16 + (lane & 15);
      int wpix = wyp*72 + wxb + pcol;
      int sz = wpix & 7;
      f32x4 acc;
      #pragma unroll
      for (int r = 0; r < 4; ++r) acc[r] = boutd[row0 + r];
      h8 b0 = *(const h8*)&qs[pcol][(lane >> 4)*8];
      h8 b1 = *(const h8*)&qs[pcol][32 + (lane >> 4)*8];
      h8 b2 = *(const h8*)&win[(wpix << 6) + ((((lane >> 4)    ) ^ sz) << 3)];
      h8 b3 = *(const h8*)&win[(wpix << 6) + ((((lane >> 4) + 4) ^ sz) << 3)];
      acc = __builtin_amdgcn_mfma_f32_16x16x32_f16(A6[(m2*4+0)*64 + lane], b0, acc, 0, 0, 0);
      acc = __builtin_amdgcn_mfma_f32_16x16x32_f16(A6[(m2*4+1)*64 + lane], b1, acc, 0, 0, 0);
      acc = __builtin_amdgcn_mfma_f32_16x16x32_f16(A6[(m2*4+2)*64 + lane], b2, acc, 0, 0, 0);
      acc = __builtin_amdgcn_mfma_f32_16x16x32_f16(A6[(m2*4+3)*64 + lane], b3, acc, 0, 0, 0);
      #pragma unroll
      for (int r = 0; r < 4; ++r) ob[(row0 + r)*HW + pcol] = acc[r];
    }
  }
}

extern "C" void kernel_launch(void* const* d_in, const int* in_sizes, int n_in,
                              void* d_out, int out_size, void* d_ws, size_t ws_size,
                              hipStream_t stream)
{
  const float* x    = (const float*)d_in[0];
  const float* alpha= (const float*)d_in[1];
  const float* offw = (const float*)d_in[2];
  const float* offb = (const float*)d_in[3];
  const float* q_dw = (const float*)d_in[4];
  const float* q_pw = (const float*)d_in[5];
  const float* q_pb = (const float*)d_in[6];
  const float* k_dw = (const float*)d_in[7];
  const float* k_pw = (const float*)d_in[8];
  const float* v_dw = (const float*)d_in[10];
  const float* v_pw = (const float*)d_in[11];
  const float* v_pb = (const float*)d_in[12];
  const float* o_dw = (const float*)d_in[13];
  const float* o_pw = (const float*)d_in[14];
  const float* o_pb = (const float*)d_in[15];
  float* out = (float*)d_out;

  char* ws        = (char*)d_ws;
  _Float16* xt    = (_Float16*)ws;                          // 8,388,608 B
  _Float16* Apack2= (_Float16*)(ws + (size_t)4*HW*64*2);    // 12288 B
  _Float16* Apack6= Apack2 + 6144;                          // 16384 B
  float* bias96   = (float*)(Apack6 + 8192);
  float* boutd    = bias96 + 96;

  prep_kernel<<<1081, 256, 0, stream>>>(x, xt, alpha, q_dw, q_pw, q_pb, k_dw, k_pw,
                                        offw, offb, v_dw, v_pw, v_pb,
                                        o_dw, o_pw, o_pb,
                                        Apack2, Apack6, bias96, boutd);
  dam_kernel<<<1024, 512, 0, stream>>>(xt, Apack2, Apack6, bias96, boutd, out);
}

// Round 14
// 29.849 us; speedup vs baseline: 1.0775x; 1.0775x over previous
//
#include <hip/hip_runtime.h>

#define HW (128*128)
#define CHW (64*HW)

typedef _Float16 h2 __attribute__((ext_vector_type(2)));
typedef _Float16 h4 __attribute__((ext_vector_type(4)));
typedef _Float16 h8 __attribute__((ext_vector_type(8)));
typedef float f32x4 __attribute__((ext_vector_type(4)));

union H8P { h8 v; h2 p[4]; };
union H4P { h4 v; h2 p[2]; int2 i; };

#if !__has_builtin(__builtin_amdgcn_fdot2)
__device__ __forceinline__ float __builtin_amdgcn_fdot2(h2 a, h2 b, float c, bool) {
  return c + (float)a[0]*(float)b[0] + (float)a[1]*(float)b[1];
}
#endif

// ---------------- transpose + setup fused (R10-proven + NT x-loads) ----------------
__global__ __launch_bounds__(256) void prep_kernel(
    const float* __restrict__ x, _Float16* __restrict__ xt,
    const float* __restrict__ alpha,
    const float* __restrict__ q_dw, const float* __restrict__ q_pw, const float* __restrict__ q_pb,
    const float* __restrict__ k_dw, const float* __restrict__ k_pw,
    const float* __restrict__ offw, const float* __restrict__ offb,
    const float* __restrict__ v_dw, const float* __restrict__ v_pw, const float* __restrict__ v_pb,
    const float* __restrict__ o_dw, const float* __restrict__ o_pw, const float* __restrict__ o_pb,
    _Float16* __restrict__ Apack2, _Float16* __restrict__ Apack6,
    float* __restrict__ bias96, float* __restrict__ boutd)
{
  int tid = threadIdx.x;
  if (blockIdx.x < 1024) {
    __shared__ __align__(16) float t[64][68];
    int i0 = blockIdx.x;
    int blk = (i0 & 7)*128 + (i0 >> 3);
    int b = blk >> 8; int y = (blk >> 1) & 127; int x0 = (blk & 1) << 6;
    const float* xb = x + b*CHW + y*128 + x0;
    // phase A: thread (c, q) loads 16 px of channel c as 4x f32x4 (non-temporal: x read once)
    {
      int c = tid >> 2, q = tid & 3;
      const f32x4* srcv = (const f32x4*)(xb + c*HW + q*16);
      f32x4* dst = (f32x4*)&t[c][q*16];
      #pragma unroll
      for (int i = 0; i < 4; ++i) dst[i] = __builtin_nontemporal_load(srcv + i);
    }
    __syncthreads();
    // phase B: thread (p, hc) writes 16 ch of pixel p as 2 h8 (xt stays cacheable — re-read)
    {
      int p = tid >> 2, hc = tid & 3;
      h8 o0, o1;
      #pragma unroll
      for (int j = 0; j < 8; ++j) o0[j] = (_Float16)t[hc*16 + j][p];
      #pragma unroll
      for (int j = 0; j < 8; ++j) o1[j] = (_Float16)t[hc*16 + 8 + j][p];
      h8* dstg = (h8*)(xt + (size_t)(b*HW + y*128 + x0 + p)*64 + hc*16);
      dstg[0] = o0; dstg[1] = o1;
    }
    return;
  }
  int bb = blockIdx.x - 1024;
  float a = alpha[0];
  if (bb < 24) {                       // Apack2: [6 mt][2 kt][64 lane][8]
    int e = bb*256 + tid;
    int j = e & 7, l = (e >> 3) & 63, kt = (e >> 9) & 1, mt = e >> 10;
    int row = mt*16 + (l & 15);
    int c   = kt*32 + (l >> 4)*8 + j;
    float v = 0.f;
    if (row < 64) {
      float s = 0.f;
      for (int o = 0; o < 64; ++o) s += k_pw[o*64+row]*q_pw[o*64+c];
      v = k_dw[row]*q_dw[c]*s;
    } else if (row < 82) {
      v = offw[(row-64)*64 + c];
    }
    Apack2[e] = (_Float16)v;
  } else if (bb < 56) {                // Apack6: [4 mt][4 kt][64 lane][8]
    int e = (bb-24)*256 + tid;
    int j = e & 7, l = (e >> 3) & 63, kt = (e >> 9) & 3, mt = e >> 11;
    int o  = mt*16 + (l & 15);
    int cc = kt*32 + (l >> 4)*8 + j;
    float v;
    if (cc < 64) {
      float s = 0.f;
      for (int h = 0; h < 64; ++h) s += o_pw[o*64+h]*o_dw[h]*v_pw[h*64+cc];
      v = a*v_dw[cc]*s;
    } else {
      int c2 = cc - 64;
      float s = 0.f;
      for (int h = 0; h < 64; ++h) s += o_pw[o*64+h]*o_dw[h]*q_pw[h*64+c2];
      v = q_dw[c2]*s;
    }
    Apack6[e] = (_Float16)v;
  } else {
    if (tid < 96) {
      float v = 0.f;
      if (tid < 64) {
        float s = 0.f;
        for (int o = 0; o < 64; ++o) s += k_pw[o*64+tid]*q_pb[o];
        v = k_dw[tid]*s;
      } else if (tid < 82) {
        v = offb[tid-64];
      }
      bias96[tid] = v;
    } else if (tid >= 128 && tid < 192) {
      int o = tid - 128;
      float s2 = 0.f;
      for (int h = 0; h < 64; ++h) s2 += o_pw[o*64+h]*o_dw[h]*(a*v_pb[h]+q_pb[h]);
      boutd[o] = o_pb[o] + s2;
    }
  }
}

// ---------------- fused main kernel: 64 px/block, 512 threads (R10 + NT out-stores) ----
// LDS (32256 B):
//  A [0,9216):      xs f16 [64][72]                       live P1..P6
//  B [9216,18432):  qkL f16 [64][72] (P2..P3) | qs (P5..P6)
//  C [18432,23040): offsF f32 [18][64]  (P2..P2.5)
//  D [23040,32256): prm int4[576]       (P2.5..P3)
__global__ __launch_bounds__(512, 4) void dam_kernel(
  const _Float16* __restrict__ xt,
  const _Float16* __restrict__ Apack2, const _Float16* __restrict__ Apack6,
  const float* __restrict__ bias96, const float* __restrict__ boutd,
  float* __restrict__ out)
{
  __shared__ __align__(16) char lds[32256];
  _Float16 (*xs)[72]  = (_Float16 (*)[72])lds;
  _Float16 (*qkL)[72] = (_Float16 (*)[72])(lds + 9216);
  _Float16 (*qs)[72]  = (_Float16 (*)[72])(lds + 9216);
  float (*offsF)[64]  = (float (*)[64])(lds + 18432);
  int4* prm           = (int4*)(lds + 23040);          // [576]

  int i0 = blockIdx.x;
  int blk = (i0 & 7)*128 + (i0 >> 3);      // XCD swizzle (matches prep)
  int b = blk >> 8; int y = (blk >> 1) & 127; int x0 = (blk & 1) << 6;
  int tid = threadIdx.x;
  int g = tid >> 6;
  int wg = __builtin_amdgcn_readfirstlane(g);
  int lane = tid & 63;

  // ---- P1: stage x tile [p][c] f16 straight from xt (contiguous 8 KB) ----
  {
    const h8* src = (const h8*)(xt + (size_t)(b*HW + y*128 + x0)*64);
    h8 v = src[tid];
    *(h8*)&xs[tid >> 3][(tid & 7)*8] = v;
  }
  __syncthreads();

  // ---- P2: [qk | offsets] = A2 @ x_tile via MFMA. M=96, K=64, N=64 ----
  {
    const h8* A2 = (const h8*)Apack2;
    #pragma unroll
    for (int i = 0; i < 3; ++i) {
      int t = wg*3 + i; int m = t >> 2, n = t & 3;
      int row0 = m*16 + (lane >> 4)*4;
      int pcol = n*16 + (lane & 15);
      f32x4 acc;
      #pragma unroll
      for (int r = 0; r < 4; ++r) acc[r] = bias96[row0 + r];
      h8 b0 = *(const h8*)&xs[pcol][(lane >> 4)*8];
      h8 b1 = *(const h8*)&xs[pcol][32 + (lane >> 4)*8];
      acc = __builtin_amdgcn_mfma_f32_16x16x32_f16(A2[(m*2+0)*64 + lane], b0, acc, 0, 0, 0);
      acc = __builtin_amdgcn_mfma_f32_16x16x32_f16(A2[(m*2+1)*64 + lane], b1, acc, 0, 0, 0);
      if (m < 4) {
        h4 v;
        #pragma unroll
        for (int r = 0; r < 4; ++r) v[r] = (_Float16)acc[r];
        *(h4*)&qkL[pcol][m*16 + (lane >> 4)*4] = v;
      } else {
        #pragma unroll
        for (int r = 0; r < 4; ++r) {
          int row = row0 + r;
          if (row < 82) offsF[row - 64][pcol] = acc[r];
        }
      }
    }
  }
  __syncthreads();

  // ---- P2.5: per-(k,p) sampling params computed ONCE -> prm[576] ----
  #pragma unroll
  for (int pass = 0; pass < 2; ++pass) {
    int e = tid + pass*512;
    if (e < 576) {
      int k = e >> 6, pp = e & 63;
      float dx = offsF[k][pp];
      float dy = offsF[9+k][pp];
      float fx = (float)(x0 + pp);
      float fy = (float)y;
      float gx = 2.0f*(fx + dx)/127.0f - 1.0f;
      float gy = 2.0f*(fy + dy)/127.0f - 1.0f;
      float ix = ((gx + 1.0f)*128.0f - 1.0f)*0.5f;
      float iy = ((gy + 1.0f)*128.0f - 1.0f)*0.5f;
      float x0f = floorf(ix), y0f = floorf(iy);
      float wx = ix - x0f, wy = iy - y0f;
      int xi = (int)x0f, yi = (int)y0f;
      bool vx0 = (xi >= 0) && (xi < 128);
      bool vx1 = (xi >= -1) && (xi < 127);
      bool vy0 = (yi >= 0) && (yi < 128);
      bool vy1 = (yi >= -1) && (yi < 127);
      H4P w;
      w.v[0] = (_Float16)((1.f-wy)*(1.f-wx)*((vy0&&vx0)?1.f:0.f));
      w.v[1] = (_Float16)((1.f-wy)*wx      *((vy0&&vx1)?1.f:0.f));
      w.v[2] = (_Float16)(wy*(1.f-wx)      *((vy1&&vx0)?1.f:0.f));
      w.v[3] = (_Float16)(wy*wx            *((vy1&&vx1)?1.f:0.f));
      int xc0 = min(max(xi,0),127), xc1 = min(max(xi+1,0),127);
      int yc0 = min(max(yi,0),127), yc1 = min(max(yi+1,0),127);
      int4 pr;
      pr.x = (yc0*128 + xc0)*64;
      pr.y = (xc1 - xc0)*64 | (((yc1 - yc0)*8192) << 16);
      pr.z = w.i.x;
      pr.w = w.i.y;
      prm[e] = pr;
    }
  }
  // lane mapping for P3: pixel pxl, channel chunk ch8
  int pxl = wg*8 + (lane >> 3);
  int ch8 = (lane & 7)*8;
  H8P qkh; qkh.v = *(const h8*)&qkL[pxl][ch8];
  __syncthreads();      // prm ready

  const _Float16* xtb = xt + (size_t)b*HW*64 + ch8;

  // ---- P3: sampling, 3-k batches (12 corner loads in flight per batch). ----
  // 8 consecutive lanes read one contiguous 128B channel row per corner.
  h2 smp[9][4];
  float sarr[9];
  #pragma unroll
  for (int kb = 0; kb < 3; ++kb) {
    int4 pr[3];
    #pragma unroll
    for (int u = 0; u < 3; ++u) pr[u] = prm[(kb*3+u)*64 + pxl];
    H8P A[3], Bc[3], Cc[3], D[3];
    #pragma unroll
    for (int u = 0; u < 3; ++u) {
      int dxs = pr[u].y & 0xFFFF;
      int dys = pr[u].y >> 16;
      const _Float16* base = xtb + pr[u].x;
      A[u].v  = *(const h8*)(base);
      Bc[u].v = *(const h8*)(base + dxs);
      Cc[u].v = *(const h8*)(base + dys);
      D[u].v  = *(const h8*)(base + dys + dxs);
    }
    #pragma unroll
    for (int u = 0; u < 3; ++u) {
      int k = kb*3 + u;
      H4P w; w.i.x = pr[u].z; w.i.y = pr[u].w;
      h2 w0h; w0h[0] = w.v[0]; w0h[1] = w.v[0];
      h2 w1h; w1h[0] = w.v[1]; w1h[1] = w.v[1];
      h2 w2h; w2h[0] = w.v[2]; w2h[1] = w.v[2];
      h2 w3h; w3h[0] = w.v[3]; w3h[1] = w.v[3];
      float s = 0.f;
      #pragma unroll
      for (int j = 0; j < 4; ++j) {
        h2 v = A[u].p[j]*w0h + Bc[u].p[j]*w1h + Cc[u].p[j]*w2h + D[u].p[j]*w3h;
        smp[k][j] = v;
        s = __builtin_amdgcn_fdot2(v, qkh.p[j], s, false);
      }
      s += __shfl_xor(s, 1, 64);
      s += __shfl_xor(s, 2, 64);
      s += __shfl_xor(s, 4, 64);
      sarr[k] = s;
    }
  }

  // ---- P4: softmax over k, fully register-local ----
  float m = sarr[0];
  #pragma unroll
  for (int k = 1; k < 9; ++k) m = fmaxf(m, sarr[k]);
  float ssum = 0.f;
  #pragma unroll
  for (int k = 0; k < 9; ++k) { float e2 = __expf(sarr[k]-m); ssum += e2; sarr[k] = e2; }
  float inv = 1.f/ssum;

  // ---- P5: S = sum_k attn_k * smp_k (registers) ----
  h2 S2[4];
  #pragma unroll
  for (int j = 0; j < 4; ++j) { S2[j][0] = (_Float16)0.f; S2[j][1] = (_Float16)0.f; }
  #pragma unroll
  for (int k = 0; k < 9; ++k) {
    _Float16 akh = (_Float16)(sarr[k]*inv);
    h2 ak; ak[0] = akh; ak[1] = akh;
    #pragma unroll
    for (int j = 0; j < 4; ++j) S2[j] = S2[j] + ak*smp[k][j];
  }
  __syncthreads();      // all waves done reading qkL/prm; safe to overwrite with qs
  {
    H8P sv;
    sv.p[0] = S2[0]; sv.p[1] = S2[1]; sv.p[2] = S2[2]; sv.p[3] = S2[3];
    *(h8*)&qs[pxl][ch8] = sv.v;
  }
  __syncthreads();

  // ---- P6: out = A6 @ [S; x] + bout via MFMA; non-temporal stores (out write-once) ----
  {
    const h8* A6 = (const h8*)Apack6;
    float* ob = out + b*CHW + y*128 + x0;
    #pragma unroll
    for (int i = 0; i < 2; ++i) {
      int t = wg*2 + i; int m2 = t >> 2, n = t & 3;
      int row0 = m2*16 + (lane >> 4)*4;
      int pcol = n*16 + (lane & 15);
      f32x4 acc;
      #pragma unroll
      for (int r = 0; r < 4; ++r) acc[r] = boutd[row0 + r];
      h8 b0 = *(const h8*)&qs[pcol][(lane >> 4)*8];
      h8 b1 = *(const h8*)&qs[pcol][32 + (lane >> 4)*8];
      h8 b2 = *(const h8*)&xs[pcol][(lane >> 4)*8];
      h8 b3 = *(const h8*)&xs[pcol][32 + (lane >> 4)*8];
      acc = __builtin_amdgcn_mfma_f32_16x16x32_f16(A6[(m2*4+0)*64 + lane], b0, acc, 0, 0, 0);
      acc = __builtin_amdgcn_mfma_f32_16x16x32_f16(A6[(m2*4+1)*64 + lane], b1, acc, 0, 0, 0);
      acc = __builtin_amdgcn_mfma_f32_16x16x32_f16(A6[(m2*4+2)*64 + lane], b2, acc, 0, 0, 0);
      acc = __builtin_amdgcn_mfma_f32_16x16x32_f16(A6[(m2*4+3)*64 + lane], b3, acc, 0, 0, 0);
      #pragma unroll
      for (int r = 0; r < 4; ++r)
        __builtin_nontemporal_store(acc[r], &ob[(row0 + r)*HW + pcol]);
    }
  }
}

extern "C" void kernel_launch(void* const* d_in, const int* in_sizes, int n_in,
                              void* d_out, int out_size, void* d_ws, size_t ws_size,
                              hipStream_t stream)
{
  const float* x    = (const float*)d_in[0];
  const float* alpha= (const float*)d_in[1];
  const float* offw = (const float*)d_in[2];
  const float* offb = (const float*)d_in[3];
  const float* q_dw = (const float*)d_in[4];
  const float* q_pw = (const float*)d_in[5];
  const float* q_pb = (const float*)d_in[6];
  const float* k_dw = (const float*)d_in[7];
  const float* k_pw = (const float*)d_in[8];
  const float* v_dw = (const float*)d_in[10];
  const float* v_pw = (const float*)d_in[11];
  const float* v_pb = (const float*)d_in[12];
  const float* o_dw = (const float*)d_in[13];
  const float* o_pw = (const float*)d_in[14];
  const float* o_pb = (const float*)d_in[15];
  float* out = (float*)d_out;

  char* ws        = (char*)d_ws;
  _Float16* xt    = (_Float16*)ws;                          // 8,388,608 B
  _Float16* Apack2= (_Float16*)(ws + (size_t)4*HW*64*2);    // 12288 B
  _Float16* Apack6= Apack2 + 6144;                          // 16384 B
  float* bias96   = (float*)(Apack6 + 8192);
  float* boutd    = bias96 + 96;

  prep_kernel<<<1081, 256, 0, stream>>>(x, xt, alpha, q_dw, q_pw, q_pb, k_dw, k_pw,
                                        offw, offb, v_dw, v_pw, v_pb,
                                        o_dw, o_pw, o_pb,
                                        Apack2, Apack6, bias96, boutd);
  dam_kernel<<<1024, 512, 0, stream>>>(xt, Apack2, Apack6, bias96, boutd, out);
}

// Round 15
// 28.879 us; speedup vs baseline: 1.1137x; 1.0336x over previous
//
#include <hip/hip_runtime.h>

#define HW (128*128)
#define CHW (64*HW)

typedef _Float16 h2 __attribute__((ext_vector_type(2)));
typedef _Float16 h4 __attribute__((ext_vector_type(4)));
typedef _Float16 h8 __attribute__((ext_vector_type(8)));
typedef float f32x4 __attribute__((ext_vector_type(4)));

union H8P { h8 v; h2 p[4]; };
union H4P { h4 v; h2 p[2]; int2 i; };

#if !__has_builtin(__builtin_amdgcn_fdot2)
__device__ __forceinline__ float __builtin_amdgcn_fdot2(h2 a, h2 b, float c, bool) {
  return c + (float)a[0]*(float)b[0] + (float)a[1]*(float)b[1];
}
#endif

// ---------------- transpose + setup fused (R10-proven) ----------------
__global__ __launch_bounds__(256) void prep_kernel(
    const float* __restrict__ x, _Float16* __restrict__ xt,
    const float* __restrict__ alpha,
    const float* __restrict__ q_dw, const float* __restrict__ q_pw, const float* __restrict__ q_pb,
    const float* __restrict__ k_dw, const float* __restrict__ k_pw,
    const float* __restrict__ offw, const float* __restrict__ offb,
    const float* __restrict__ v_dw, const float* __restrict__ v_pw, const float* __restrict__ v_pb,
    const float* __restrict__ o_dw, const float* __restrict__ o_pw, const float* __restrict__ o_pb,
    _Float16* __restrict__ Apack2, _Float16* __restrict__ Apack6,
    float* __restrict__ bias96, float* __restrict__ boutd)
{
  int tid = threadIdx.x;
  if (blockIdx.x < 1024) {
    __shared__ __align__(16) float t[64][68];
    int i0 = blockIdx.x;
    int blk = (i0 & 7)*128 + (i0 >> 3);
    int b = blk >> 8; int y = (blk >> 1) & 127; int x0 = (blk & 1) << 6;
    const float* xb = x + b*CHW + y*128 + x0;
    {
      int c = tid >> 2, q = tid & 3;
      const float4* srcv = (const float4*)(xb + c*HW + q*16);
      float4* dst = (float4*)&t[c][q*16];
      #pragma unroll
      for (int i = 0; i < 4; ++i) dst[i] = srcv[i];
    }
    __syncthreads();
    {
      int p = tid >> 2, hc = tid & 3;
      h8 o0, o1;
      #pragma unroll
      for (int j = 0; j < 8; ++j) o0[j] = (_Float16)t[hc*16 + j][p];
      #pragma unroll
      for (int j = 0; j < 8; ++j) o1[j] = (_Float16)t[hc*16 + 8 + j][p];
      h8* dstg = (h8*)(xt + (size_t)(b*HW + y*128 + x0 + p)*64 + hc*16);
      dstg[0] = o0; dstg[1] = o1;
    }
    return;
  }
  int bb = blockIdx.x - 1024;
  float a = alpha[0];
  if (bb < 24) {                       // Apack2: [6 mt][2 kt][64 lane][8]
    int e = bb*256 + tid;
    int j = e & 7, l = (e >> 3) & 63, kt = (e >> 9) & 1, mt = e >> 10;
    int row = mt*16 + (l & 15);
    int c   = kt*32 + (l >> 4)*8 + j;
    float v = 0.f;
    if (row < 64) {
      float s = 0.f;
      for (int o = 0; o < 64; ++o) s += k_pw[o*64+row]*q_pw[o*64+c];
      v = k_dw[row]*q_dw[c]*s;
    } else if (row < 82) {
      v = offw[(row-64)*64 + c];
    }
    Apack2[e] = (_Float16)v;
  } else if (bb < 56) {                // Apack6: [4 mt][4 kt][64 lane][8]
    int e = (bb-24)*256 + tid;
    int j = e & 7, l = (e >> 3) & 63, kt = (e >> 9) & 3, mt = e >> 11;
    int o  = mt*16 + (l & 15);
    int cc = kt*32 + (l >> 4)*8 + j;
    float v;
    if (cc < 64) {
      float s = 0.f;
      for (int h = 0; h < 64; ++h) s += o_pw[o*64+h]*o_dw[h]*v_pw[h*64+cc];
      v = a*v_dw[cc]*s;
    } else {
      int c2 = cc - 64;
      float s = 0.f;
      for (int h = 0; h < 64; ++h) s += o_pw[o*64+h]*o_dw[h]*q_pw[h*64+c2];
      v = q_dw[c2]*s;
    }
    Apack6[e] = (_Float16)v;
  } else {
    if (tid < 96) {
      float v = 0.f;
      if (tid < 64) {
        float s = 0.f;
        for (int o = 0; o < 64; ++o) s += k_pw[o*64+tid]*q_pb[o];
        v = k_dw[tid]*s;
      } else if (tid < 82) {
        v = offb[tid-64];
      }
      bias96[tid] = v;
    } else if (tid >= 128 && tid < 192) {
      int o = tid - 128;
      float s2 = 0.f;
      for (int h = 0; h < 64; ++h) s2 += o_pw[o*64+h]*o_dw[h]*(a*v_pb[h]+q_pb[h]);
      boutd[o] = o_pb[o] + s2;
    }
  }
}

// ---------------- fused main kernel: 32 px/block, 256 threads, 2048 blocks -------------
// LDS (16128 B):
//  A [0,4608):      xs f16 [32][72]                       live P1..P6
//  B [4608,9216):   qkL f16 [32][72] (P2..P3) | qs (P5..P6)
//  C [9216,11520):  offsF f32 [18][32]  (P2..P2.5)
//  D [11520,16128): prm int4[288]       (P2.5..P3)
// 5 blocks/CU (launch_bounds 256,5) -> 20 waves/CU.
__global__ __launch_bounds__(256, 5) void dam_kernel(
  const _Float16* __restrict__ xt,
  const _Float16* __restrict__ Apack2, const _Float16* __restrict__ Apack6,
  const float* __restrict__ bias96, const float* __restrict__ boutd,
  float* __restrict__ out)
{
  __shared__ __align__(16) char lds[16128];
  _Float16 (*xs)[72]  = (_Float16 (*)[72])lds;
  _Float16 (*qkL)[72] = (_Float16 (*)[72])(lds + 4608);
  _Float16 (*qs)[72]  = (_Float16 (*)[72])(lds + 4608);
  float (*offsF)[32]  = (float (*)[32])(lds + 9216);
  int4* prm           = (int4*)(lds + 11520);          // [288]

  int i0 = blockIdx.x;
  int blk = (i0 & 7)*256 + (i0 >> 3);      // XCD swizzle: 64 consecutive rows per XCD
  int b = blk >> 9; int y = (blk >> 2) & 127; int x0 = (blk & 3) << 5;
  int tid = threadIdx.x;
  int g = tid >> 6;
  int wg = __builtin_amdgcn_readfirstlane(g);
  int lane = tid & 63;

  // ---- P1: stage x tile [p][c] f16 straight from xt (contiguous 4 KB) ----
  {
    const h8* src = (const h8*)(xt + (size_t)(b*HW + y*128 + x0)*64);
    h8 v = src[tid];
    *(h8*)&xs[tid >> 3][(tid & 7)*8] = v;
  }
  __syncthreads();

  // ---- P2: [qk | offsets] = A2 @ x_tile via MFMA. M=96, K=64, N=32 ----
  // 12 tiles (6m x 2n); wave wg does t = 3wg..3wg+2, m = t>>1, n = t&1
  {
    const h8* A2 = (const h8*)Apack2;
    #pragma unroll
    for (int i = 0; i < 3; ++i) {
      int t = wg*3 + i; int m = t >> 1, n = t & 1;
      int row0 = m*16 + (lane >> 4)*4;
      int pcol = n*16 + (lane & 15);
      f32x4 acc;
      #pragma unroll
      for (int r = 0; r < 4; ++r) acc[r] = bias96[row0 + r];
      h8 b0 = *(const h8*)&xs[pcol][(lane >> 4)*8];
      h8 b1 = *(const h8*)&xs[pcol][32 + (lane >> 4)*8];
      acc = __builtin_amdgcn_mfma_f32_16x16x32_f16(A2[(m*2+0)*64 + lane], b0, acc, 0, 0, 0);
      acc = __builtin_amdgcn_mfma_f32_16x16x32_f16(A2[(m*2+1)*64 + lane], b1, acc, 0, 0, 0);
      if (m < 4) {
        h4 v;
        #pragma unroll
        for (int r = 0; r < 4; ++r) v[r] = (_Float16)acc[r];
        *(h4*)&qkL[pcol][m*16 + (lane >> 4)*4] = v;
      } else {
        #pragma unroll
        for (int r = 0; r < 4; ++r) {
          int row = row0 + r;
          if (row < 82) offsF[row - 64][pcol] = acc[r];
        }
      }
    }
  }
  __syncthreads();

  // ---- P2.5: per-(k,p) sampling params computed ONCE -> prm[288] ----
  #pragma unroll
  for (int pass = 0; pass < 2; ++pass) {
    int e = tid + pass*256;
    if (e < 288) {
      int k = e >> 5, pp = e & 31;
      float dx = offsF[k][pp];
      float dy = offsF[9+k][pp];
      float fx = (float)(x0 + pp);
      float fy = (float)y;
      float gx = 2.0f*(fx + dx)/127.0f - 1.0f;
      float gy = 2.0f*(fy + dy)/127.0f - 1.0f;
      float ix = ((gx + 1.0f)*128.0f - 1.0f)*0.5f;
      float iy = ((gy + 1.0f)*128.0f - 1.0f)*0.5f;
      float x0f = floorf(ix), y0f = floorf(iy);
      float wx = ix - x0f, wy = iy - y0f;
      int xi = (int)x0f, yi = (int)y0f;
      bool vx0 = (xi >= 0) && (xi < 128);
      bool vx1 = (xi >= -1) && (xi < 127);
      bool vy0 = (yi >= 0) && (yi < 128);
      bool vy1 = (yi >= -1) && (yi < 127);
      H4P w;
      w.v[0] = (_Float16)((1.f-wy)*(1.f-wx)*((vy0&&vx0)?1.f:0.f));
      w.v[1] = (_Float16)((1.f-wy)*wx      *((vy0&&vx1)?1.f:0.f));
      w.v[2] = (_Float16)(wy*(1.f-wx)      *((vy1&&vx0)?1.f:0.f));
      w.v[3] = (_Float16)(wy*wx            *((vy1&&vx1)?1.f:0.f));
      int xc0 = min(max(xi,0),127), xc1 = min(max(xi+1,0),127);
      int yc0 = min(max(yi,0),127), yc1 = min(max(yi+1,0),127);
      int4 pr;
      pr.x = (yc0*128 + xc0)*64;
      pr.y = (xc1 - xc0)*64 | (((yc1 - yc0)*8192) << 16);
      pr.z = w.i.x;
      pr.w = w.i.y;
      prm[e] = pr;
    }
  }
  // lane mapping for P3: pixel pxl (0..31), channel chunk ch8
  int pxl = wg*8 + (lane >> 3);
  int ch8 = (lane & 7)*8;
  H8P qkh; qkh.v = *(const h8*)&qkL[pxl][ch8];
  __syncthreads();      // prm ready

  const _Float16* xtb = xt + (size_t)b*HW*64 + ch8;

  // ---- P3: sampling, 3-k batches (12 corner loads in flight per batch). ----
  h2 smp[9][4];
  float sarr[9];
  #pragma unroll
  for (int kb = 0; kb < 3; ++kb) {
    int4 pr[3];
    #pragma unroll
    for (int u = 0; u < 3; ++u) pr[u] = prm[(kb*3+u)*32 + pxl];
    H8P A[3], Bc[3], Cc[3], D[3];
    #pragma unroll
    for (int u = 0; u < 3; ++u) {
      int dxs = pr[u].y & 0xFFFF;
      int dys = pr[u].y >> 16;
      const _Float16* base = xtb + pr[u].x;
      A[u].v  = *(const h8*)(base);
      Bc[u].v = *(const h8*)(base + dxs);
      Cc[u].v = *(const h8*)(base + dys);
      D[u].v  = *(const h8*)(base + dys + dxs);
    }
    #pragma unroll
    for (int u = 0; u < 3; ++u) {
      int k = kb*3 + u;
      H4P w; w.i.x = pr[u].z; w.i.y = pr[u].w;
      h2 w0h; w0h[0] = w.v[0]; w0h[1] = w.v[0];
      h2 w1h; w1h[0] = w.v[1]; w1h[1] = w.v[1];
      h2 w2h; w2h[0] = w.v[2]; w2h[1] = w.v[2];
      h2 w3h; w3h[0] = w.v[3]; w3h[1] = w.v[3];
      float s = 0.f;
      #pragma unroll
      for (int j = 0; j < 4; ++j) {
        h2 v = A[u].p[j]*w0h + Bc[u].p[j]*w1h + Cc[u].p[j]*w2h + D[u].p[j]*w3h;
        smp[k][j] = v;
        s = __builtin_amdgcn_fdot2(v, qkh.p[j], s, false);
      }
      s += __shfl_xor(s, 1, 64);
      s += __shfl_xor(s, 2, 64);
      s += __shfl_xor(s, 4, 64);
      sarr[k] = s;
    }
  }

  // ---- P4: softmax over k, fully register-local ----
  float m = sarr[0];
  #pragma unroll
  for (int k = 1; k < 9; ++k) m = fmaxf(m, sarr[k]);
  float ssum = 0.f;
  #pragma unroll
  for (int k = 0; k < 9; ++k) { float e2 = __expf(sarr[k]-m); ssum += e2; sarr[k] = e2; }
  float inv = 1.f/ssum;

  // ---- P5: S = sum_k attn_k * smp_k (registers) ----
  h2 S2[4];
  #pragma unroll
  for (int j = 0; j < 4; ++j) { S2[j][0] = (_Float16)0.f; S2[j][1] = (_Float16)0.f; }
  #pragma unroll
  for (int k = 0; k < 9; ++k) {
    _Float16 akh = (_Float16)(sarr[k]*inv);
    h2 ak; ak[0] = akh; ak[1] = akh;
    #pragma unroll
    for (int j = 0; j < 4; ++j) S2[j] = S2[j] + ak*smp[k][j];
  }
  __syncthreads();      // all waves done reading qkL/prm; safe to overwrite with qs
  {
    H8P sv;
    sv.p[0] = S2[0]; sv.p[1] = S2[1]; sv.p[2] = S2[2]; sv.p[3] = S2[3];
    *(h8*)&qs[pxl][ch8] = sv.v;
  }
  __syncthreads();

  // ---- P6: out = A6 @ [S; x] + bout via MFMA. M=64, K=128, N=32 ----
  // 8 tiles (4m x 2n); wave wg does t = 2wg, 2wg+1, m2 = t>>1, n = t&1
  {
    const h8* A6 = (const h8*)Apack6;
    float* ob = out + b*CHW + y*128 + x0;
    #pragma unroll
    for (int i = 0; i < 2; ++i) {
      int t = wg*2 + i; int m2 = t >> 1, n = t & 1;
      int row0 = m2*16 + (lane >> 4)*4;
      int pcol = n*16 + (lane & 15);
      f32x4 acc;
      #pragma unroll
      for (int r = 0; r < 4; ++r) acc[r] = boutd[row0 + r];
      h8 b0 = *(const h8*)&qs[pcol][(lane >> 4)*8];
      h8 b1 = *(const h8*)&qs[pcol][32 + (lane >> 4)*8];
      h8 b2 = *(const h8*)&xs[pcol][(lane >> 4)*8];
      h8 b3 = *(const h8*)&xs[pcol][32 + (lane >> 4)*8];
      acc = __builtin_amdgcn_mfma_f32_16x16x32_f16(A6[(m2*4+0)*64 + lane], b0, acc, 0, 0, 0);
      acc = __builtin_amdgcn_mfma_f32_16x16x32_f16(A6[(m2*4+1)*64 + lane], b1, acc, 0, 0, 0);
      acc = __builtin_amdgcn_mfma_f32_16x16x32_f16(A6[(m2*4+2)*64 + lane], b2, acc, 0, 0, 0);
      acc = __builtin_amdgcn_mfma_f32_16x16x32_f16(A6[(m2*4+3)*64 + lane], b3, acc, 0, 0, 0);
      #pragma unroll
      for (int r = 0; r < 4; ++r) ob[(row0 + r)*HW + pcol] = acc[r];
    }
  }
}

extern "C" void kernel_launch(void* const* d_in, const int* in_sizes, int n_in,
                              void* d_out, int out_size, void* d_ws, size_t ws_size,
                              hipStream_t stream)
{
  const float* x    = (const float*)d_in[0];
  const float* alpha= (const float*)d_in[1];
  const float* offw = (const float*)d_in[2];
  const float* offb = (const float*)d_in[3];
  const float* q_dw = (const float*)d_in[4];
  const float* q_pw = (const float*)d_in[5];
  const float* q_pb = (const float*)d_in[6];
  const float* k_dw = (const float*)d_in[7];
  const float* k_pw = (const float*)d_in[8];
  const float* v_dw = (const float*)d_in[10];
  const float* v_pw = (const float*)d_in[11];
  const float* v_pb = (const float*)d_in[12];
  const float* o_dw = (const float*)d_in[13];
  const float* o_pw = (const float*)d_in[14];
  const float* o_pb = (const float*)d_in[15];
  float* out = (float*)d_out;

  char* ws        = (char*)d_ws;
  _Float16* xt    = (_Float16*)ws;                          // 8,388,608 B
  _Float16* Apack2= (_Float16*)(ws + (size_t)4*HW*64*2);    // 12288 B
  _Float16* Apack6= Apack2 + 6144;                          // 16384 B
  float* bias96   = (float*)(Apack6 + 8192);
  float* boutd    = bias96 + 96;

  prep_kernel<<<1081, 256, 0, stream>>>(x, xt, alpha, q_dw, q_pw, q_pb, k_dw, k_pw,
                                        offw, offb, v_dw, v_pw, v_pb,
                                        o_dw, o_pw, o_pb,
                                        Apack2, Apack6, bias96, boutd);
  dam_kernel<<<2048, 256, 0, stream>>>(xt, Apack2, Apack6, bias96, boutd, out);
}